// Round 6
// baseline (1249.314 us; speedup 1.0000x reference)
//
#include <hip/hip_runtime.h>

#define BB 16
#define NN 38400
#define SS 7
#define BPB 120              // blocks per batch
#define ROWS_PB (NN / BPB)   // 320 rows per block
#define PASSES (ROWS_PB / 32)  // 10 passes of 32 rows (4 waves x 8 rows)

__device__ __forceinline__ float wsum64(float v) {
#pragma unroll
  for (int off = 32; off > 0; off >>= 1) v += __shfl_xor(v, off);
  return v;
}

// ---------------------------------------------------------------------------
// Slot-side kernel: 112 blocks (one per (b,s)), 64 threads (lane = d).
// mode 0: init slots; mode 1: GRU+MLP update; mode 2: update + write out.
// ACCM is recovered from ACC: sum_n p*rstd*mean = (1/64) * sum_d ACC[s][d].
// ---------------------------------------------------------------------------
__global__ __launch_bounds__(64) void k_slot(
    int mode,
    const float* __restrict__ slots_init, const float* __restrict__ mu,
    const float* __restrict__ lsig,
    const float* __restrict__ ln_slot_g, const float* __restrict__ ln_slot_b,
    const float* __restrict__ ln_mlp_g, const float* __restrict__ ln_mlp_b,
    const float* __restrict__ ln_in_g, const float* __restrict__ ln_in_b,
    const float* __restrict__ Wq, const float* __restrict__ Wk,
    const float* __restrict__ Wv,
    const float* __restrict__ W_ih, const float* __restrict__ W_hh,
    const float* __restrict__ b_ih, const float* __restrict__ b_hh,
    const float* __restrict__ W1, const float* __restrict__ b1,
    const float* __restrict__ W2, const float* __restrict__ b2,
    float* __restrict__ slots, float* __restrict__ gqk,
    float* __restrict__ sc,
    float* __restrict__ ACC, float* __restrict__ Zg,
    float* __restrict__ out)
{
  const int bs = blockIdx.x;
  const int b = bs / SS, s = bs % SS;
  const int d = threadIdx.x;
  __shared__ float t0[64], t1[64], hh[128];

  float slot;
  if (mode == 0) {
    slot = mu[d] + __expf(lsig[d]) * slots_init[bs * 64 + d];
  } else {
    const float zv = Zg[b * 8 + s];
    const float ac = ACC[(b * 8 + s) * 64 + d];
    const float am = wsum64(ac) * (1.f / 64.f);  // = sum_n p*rstd*mean
    const float ubar = (ln_in_g[d] * (ac - am) + ln_in_b[d] * zv) / zv;
    t0[d] = ubar;
    __syncthreads();
    float upd = 0.f;
#pragma unroll
    for (int e = 0; e < 64; ++e) upd += t0[e] * Wv[d * 64 + e];
    const float sp = slots[bs * 64 + d];
    __syncthreads();
    t0[d] = upd;
    t1[d] = sp;
    __syncthreads();
    float s_r = b_ih[d] + b_hh[d];
    float s_z = b_ih[64 + d] + b_hh[64 + d];
    float i_n = b_ih[128 + d];
    float h_n = b_hh[128 + d];
#pragma unroll
    for (int e = 0; e < 64; ++e) {
      const float u = t0[e], p = t1[e];
      s_r += u * W_ih[d * 64 + e] + p * W_hh[d * 64 + e];
      s_z += u * W_ih[(64 + d) * 64 + e] + p * W_hh[(64 + d) * 64 + e];
      i_n += u * W_ih[(128 + d) * 64 + e];
      h_n += p * W_hh[(128 + d) * 64 + e];
    }
    const float rg = 1.f / (1.f + __expf(-s_r));
    const float zg = 1.f / (1.f + __expf(-s_z));
    const float ng = tanhf(i_n + rg * h_n);
    const float hv = (1.f - zg) * ng + zg * sp;
    const float mn = wsum64(hv) * (1.f / 64.f);
    const float dv = hv - mn;
    const float vr = wsum64(dv * dv) * (1.f / 64.f);
    const float rs = rsqrtf(vr + 1e-5f);
    const float mld = dv * rs * ln_mlp_g[d] + ln_mlp_b[d];
    __syncthreads();
    t0[d] = mld;
    __syncthreads();
    float h0 = b1[d], h1 = b1[64 + d];
#pragma unroll
    for (int e = 0; e < 64; ++e) {
      const float m = t0[e];
      h0 += m * W1[d * 64 + e];
      h1 += m * W1[(64 + d) * 64 + e];
    }
    hh[d] = fmaxf(h0, 0.f);
    hh[64 + d] = fmaxf(h1, 0.f);
    __syncthreads();
    float o = hv + b2[d];
#pragma unroll
    for (int j = 0; j < 128; ++j) o += hh[j] * W2[d * 128 + j];
    slot = o;
  }

  if (mode == 2) {
    out[bs * 64 + d] = slot;
    return;
  }
  slots[bs * 64 + d] = slot;

  // tail: LN_slot -> q -> gqk (scale & ln_in_g folded), sgq, cb
  const float mn = wsum64(slot) * (1.f / 64.f);
  const float dv = slot - mn;
  const float vr = wsum64(dv * dv) * (1.f / 64.f);
  const float rs = rsqrtf(vr + 1e-5f);
  const float sln = dv * rs * ln_slot_g[d] + ln_slot_b[d];
  __syncthreads();
  t0[d] = sln;
  __syncthreads();
  float qv = 0.f;
#pragma unroll
  for (int e = 0; e < 64; ++e) qv += t0[e] * Wq[d * 64 + e];
  __syncthreads();
  t1[d] = qv;
  __syncthreads();
  float qe = 0.f;
#pragma unroll
  for (int dd = 0; dd < 64; ++dd) qe += t1[dd] * Wk[dd * 64 + d];
  qe *= 0.125f;  // scale = D^-0.5
  const float gq = ln_in_g[d] * qe;
  gqk[(b * 8 + s) * 64 + d] = gq;
  const float sg = wsum64(gq);
  const float cb = wsum64(ln_in_b[d] * qe);
  if (d == 0) {
    sc[(b * 8 + s) * 2 + 0] = sg;
    sc[(b * 8 + s) * 2 + 1] = cb;
  }
  ACC[(b * 8 + s) * 64 + d] = 0.f;
  if (d == 0) Zg[b * 8 + s] = 0.f;
}

// ---------------------------------------------------------------------------
// Main kernel: 1920 blocks (120/batch) x 256 threads. SINGLE-PASS streaming,
// NO barriers in the main loop. Lane = (rw = lane>>3 row-in-octet,
// co = lane&7 column octet): owns cols [co*4..co*4+3] and [32+co*4..+3] of
// its row — both float4 loads perfectly coalesced per wave (2KB/2 instrs).
//   dot      : 7 logit partials vs LDS-broadcast gqk (conflict-free)
//   reduce   : 3-step shfl_xor over the 8-lane octet (9 values)
//   softmax  : per-lane on reduced values (x8 replicated, /8 at flush)
//   outer    : acc[7][8] += p*rstd * x  — from the registers holding x
// Next pass's 2 loads are prefetched before compute. One flush per block.
// ---------------------------------------------------------------------------
__global__ __launch_bounds__(256, 4) void k_main(
    const float* __restrict__ x,
    const float* __restrict__ gqk,  // [B][8][64]
    const float* __restrict__ sc,   // [B][8][2]
    float* __restrict__ ACC, float* __restrict__ Zg)
{
  __shared__ __align__(16) float qbs[512];       // 2 KB
  __shared__ __align__(16) float scr[4 * 7 * 64];  // 7 KB
  __shared__ float scs[16];

  const int t = threadIdx.x;
  const int lane = t & 63;
  const int w = t >> 6;
  const int rw = lane >> 3;  // row within 8-row wave pass
  const int co = lane & 7;   // column octet
  const int b = blockIdx.x / BPB;
  const int kb = blockIdx.x % BPB;

  qbs[t] = gqk[b * 512 + t];
  qbs[256 + t] = gqk[b * 512 + 256 + t];
  if (t < 16) scs[t] = sc[b * 16 + t];
  __syncthreads();

  float acc[7][8];
#pragma unroll
  for (int s = 0; s < 7; ++s)
#pragma unroll
    for (int j = 0; j < 8; ++j) acc[s][j] = 0.f;
  float zac[7] = {0, 0, 0, 0, 0, 0, 0};

  // this thread's stream: row = base + ps*32, cols co*4 and 32+co*4
  const float* xp =
      x + ((size_t)b * NN + kb * ROWS_PB + w * 8 + rw) * 64 + co * 4;

  float4 a0 = *reinterpret_cast<const float4*>(xp);
  float4 a1 = *reinterpret_cast<const float4*>(xp + 32);

#pragma unroll
  for (int ps = 0; ps < PASSES; ++ps) {
    // prefetch next pass
    float4 n0, n1;
    if (ps + 1 < PASSES) {
      const float* xn = xp + (size_t)(ps + 1) * 32 * 64;
      n0 = *reinterpret_cast<const float4*>(xn);
      n1 = *reinterpret_cast<const float4*>(xn + 32);
    }

    // ---- dot + LN stats ----
    float lg[7];
    float sum = a0.x + a0.y + a0.z + a0.w + a1.x + a1.y + a1.z + a1.w;
    float sq = fmaf(a0.x, a0.x, fmaf(a0.y, a0.y, fmaf(a0.z, a0.z,
               fmaf(a0.w, a0.w, fmaf(a1.x, a1.x, fmaf(a1.y, a1.y,
               fmaf(a1.z, a1.z, a1.w * a1.w)))))));
#pragma unroll
    for (int s = 0; s < 7; ++s) {
      const float4 g0 = *reinterpret_cast<const float4*>(&qbs[s * 64 + co * 4]);
      const float4 g1 =
          *reinterpret_cast<const float4*>(&qbs[s * 64 + 32 + co * 4]);
      lg[s] = fmaf(a0.x, g0.x, fmaf(a0.y, g0.y, fmaf(a0.z, g0.z,
              fmaf(a0.w, g0.w, fmaf(a1.x, g1.x, fmaf(a1.y, g1.y,
              fmaf(a1.z, g1.z, a1.w * g1.w)))))));
    }
    // ---- 3-step octet reduce (offsets 1,2,4 stay in the 8-lane group) ----
#pragma unroll
    for (int off = 1; off <= 4; off <<= 1) {
      sum += __shfl_xor(sum, off);
      sq += __shfl_xor(sq, off);
#pragma unroll
      for (int s = 0; s < 7; ++s) lg[s] += __shfl_xor(lg[s], off);
    }
    // ---- softmax (per-lane, replicated across octet) ----
    const float mean = sum * (1.f / 64.f);
    const float var = sq * (1.f / 64.f) - mean * mean;
    const float rstd = rsqrtf(var + 1e-5f);
    const float rm = rstd * mean;
    float mx = -1e30f;
#pragma unroll
    for (int s = 0; s < 7; ++s) {
      lg[s] = rstd * lg[s] - rm * scs[s * 2] + scs[s * 2 + 1];
      mx = fmaxf(mx, lg[s]);
    }
    float se = 0.f;
#pragma unroll
    for (int s = 0; s < 7; ++s) {
      lg[s] = __expf(lg[s] - mx);
      se += lg[s];
    }
    const float inv = 1.f / se;
    // ---- outer product into persistent registers ----
#pragma unroll
    for (int s = 0; s < 7; ++s) {
      const float p = lg[s] * inv + 1e-8f;
      const float pr = p * rstd;
      zac[s] += p;  // 8x octet-replicated; corrected at flush
      acc[s][0] = fmaf(pr, a0.x, acc[s][0]);
      acc[s][1] = fmaf(pr, a0.y, acc[s][1]);
      acc[s][2] = fmaf(pr, a0.z, acc[s][2]);
      acc[s][3] = fmaf(pr, a0.w, acc[s][3]);
      acc[s][4] = fmaf(pr, a1.x, acc[s][4]);
      acc[s][5] = fmaf(pr, a1.y, acc[s][5]);
      acc[s][6] = fmaf(pr, a1.z, acc[s][6]);
      acc[s][7] = fmaf(pr, a1.w, acc[s][7]);
    }
    a0 = n0;
    a1 = n1;
  }

  // ---- flush (once per block) ----
  // sum across the 8 row-octets of the wave (lanes with same co)
#pragma unroll
  for (int s = 0; s < 7; ++s)
#pragma unroll
    for (int j = 0; j < 8; ++j) {
      acc[s][j] += __shfl_xor(acc[s][j], 8);
      acc[s][j] += __shfl_xor(acc[s][j], 16);
      acc[s][j] += __shfl_xor(acc[s][j], 32);
    }
  if (rw == 0) {  // lanes 0..7: co = lane
#pragma unroll
    for (int s = 0; s < 7; ++s) {
      const float4 v0 = {acc[s][0], acc[s][1], acc[s][2], acc[s][3]};
      const float4 v1 = {acc[s][4], acc[s][5], acc[s][6], acc[s][7]};
      *reinterpret_cast<float4*>(&scr[(w * 7 + s) * 64 + co * 4]) = v0;
      *reinterpret_cast<float4*>(&scr[(w * 7 + s) * 64 + 32 + co * 4]) = v1;
    }
  }
  __syncthreads();
  {
    const int d = lane;
    float v0 = scr[(0 * 7 + w) * 64 + d] + scr[(1 * 7 + w) * 64 + d] +
               scr[(2 * 7 + w) * 64 + d] + scr[(3 * 7 + w) * 64 + d];
    atomicAdd(&ACC[(b * 8 + w) * 64 + d], v0);
    if (w < 3) {
      float v1 = scr[(0 * 7 + w + 4) * 64 + d] + scr[(1 * 7 + w + 4) * 64 + d] +
                 scr[(2 * 7 + w + 4) * 64 + d] + scr[(3 * 7 + w + 4) * 64 + d];
      atomicAdd(&ACC[(b * 8 + w + 4) * 64 + d], v1);
    }
  }
  float zv = 0.f;
#pragma unroll
  for (int s = 0; s < 7; ++s) {
    const float z = wsum64(zac[s]) * 0.125f;  // undo 8x octet replication
    if (lane == s) zv = z;
  }
  if (lane < 7) atomicAdd(&Zg[b * 8 + lane], zv);
}

extern "C" void kernel_launch(void* const* d_in, const int* in_sizes, int n_in,
                              void* d_out, int out_size, void* d_ws,
                              size_t ws_size, hipStream_t stream) {
  const float* inputs     = (const float*)d_in[0];
  const float* slots_init = (const float*)d_in[1];
  const float* slots_mu   = (const float*)d_in[2];
  const float* slots_lsig = (const float*)d_in[3];
  const float* ln_in_g    = (const float*)d_in[4];
  const float* ln_in_b    = (const float*)d_in[5];
  const float* ln_slot_g  = (const float*)d_in[6];
  const float* ln_slot_b  = (const float*)d_in[7];
  const float* ln_mlp_g   = (const float*)d_in[8];
  const float* ln_mlp_b   = (const float*)d_in[9];
  const float* Wq   = (const float*)d_in[10];
  const float* Wk   = (const float*)d_in[11];
  const float* Wv   = (const float*)d_in[12];
  const float* W_ih = (const float*)d_in[13];
  const float* W_hh = (const float*)d_in[14];
  const float* b_ih = (const float*)d_in[15];
  const float* b_hh = (const float*)d_in[16];
  const float* W1   = (const float*)d_in[17];
  const float* b1   = (const float*)d_in[18];
  const float* W2   = (const float*)d_in[19];
  const float* b2   = (const float*)d_in[20];

  float* ws    = (float*)d_ws;
  float* slots = ws;            // B*S*64 = 7168
  float* gqk   = ws + 7168;     // B*8*64 = 8192
  float* sc    = gqk + 8192;    // B*8*2  = 256
  float* ACC   = sc + 256;      // B*8*64 = 8192
  float* Zg    = ACC + 8192;    // B*8    = 128

  float* out = (float*)d_out;

#define SLOT_ARGS                                                          \
  slots_init, slots_mu, slots_lsig, ln_slot_g, ln_slot_b, ln_mlp_g,        \
      ln_mlp_b, ln_in_g, ln_in_b, Wq, Wk, Wv, W_ih, W_hh, b_ih, b_hh, W1,  \
      b1, W2, b2, slots, gqk, sc, ACC, Zg, out

  k_slot<<<112, 64, 0, stream>>>(0, SLOT_ARGS);
  for (int it = 0; it < 3; ++it) {
    k_main<<<BB * BPB, 256, 0, stream>>>(inputs, gqk, sc, ACC, Zg);
    k_slot<<<112, 64, 0, stream>>>(it == 2 ? 2 : 1, SLOT_ARGS);
  }
#undef SLOT_ARGS
}

// Round 7
// 829.322 us; speedup vs baseline: 1.5064x; 1.5064x over previous
//
#include <hip/hip_runtime.h>

#define BB 16
#define NN 38400
#define SS 7
#define BPB 120              // blocks per batch
#define ROWS_PB (NN / BPB)   // 320 rows per block
#define PASSES (ROWS_PB / 32)  // 10 passes of 32 rows (4 waves x 8 rows)

__device__ __forceinline__ float wsum64(float v) {
#pragma unroll
  for (int off = 32; off > 0; off >>= 1) v += __shfl_xor(v, off);
  return v;
}

// ---------------------------------------------------------------------------
// Slot-side kernel: 112 blocks (one per (b,s)), 64 threads (lane = d).
// mode 0: init slots; mode 1: GRU+MLP update; mode 2: update + write out.
// ACCM is recovered from ACC: sum_n p*rstd*mean = (1/64) * sum_d ACC[s][d].
// ---------------------------------------------------------------------------
__global__ __launch_bounds__(64) void k_slot(
    int mode,
    const float* __restrict__ slots_init, const float* __restrict__ mu,
    const float* __restrict__ lsig,
    const float* __restrict__ ln_slot_g, const float* __restrict__ ln_slot_b,
    const float* __restrict__ ln_mlp_g, const float* __restrict__ ln_mlp_b,
    const float* __restrict__ ln_in_g, const float* __restrict__ ln_in_b,
    const float* __restrict__ Wq, const float* __restrict__ Wk,
    const float* __restrict__ Wv,
    const float* __restrict__ W_ih, const float* __restrict__ W_hh,
    const float* __restrict__ b_ih, const float* __restrict__ b_hh,
    const float* __restrict__ W1, const float* __restrict__ b1,
    const float* __restrict__ W2, const float* __restrict__ b2,
    float* __restrict__ slots, float* __restrict__ gqk,
    float* __restrict__ sc,
    float* __restrict__ ACC, float* __restrict__ Zg,
    float* __restrict__ out)
{
  const int bs = blockIdx.x;
  const int b = bs / SS, s = bs % SS;
  const int d = threadIdx.x;
  __shared__ float t0[64], t1[64], hh[128];

  float slot;
  if (mode == 0) {
    slot = mu[d] + __expf(lsig[d]) * slots_init[bs * 64 + d];
  } else {
    const float zv = Zg[b * 8 + s];
    const float ac = ACC[(b * 8 + s) * 64 + d];
    const float am = wsum64(ac) * (1.f / 64.f);  // = sum_n p*rstd*mean
    const float ubar = (ln_in_g[d] * (ac - am) + ln_in_b[d] * zv) / zv;
    t0[d] = ubar;
    __syncthreads();
    float upd = 0.f;
#pragma unroll
    for (int e = 0; e < 64; ++e) upd += t0[e] * Wv[d * 64 + e];
    const float sp = slots[bs * 64 + d];
    __syncthreads();
    t0[d] = upd;
    t1[d] = sp;
    __syncthreads();
    float s_r = b_ih[d] + b_hh[d];
    float s_z = b_ih[64 + d] + b_hh[64 + d];
    float i_n = b_ih[128 + d];
    float h_n = b_hh[128 + d];
#pragma unroll
    for (int e = 0; e < 64; ++e) {
      const float u = t0[e], p = t1[e];
      s_r += u * W_ih[d * 64 + e] + p * W_hh[d * 64 + e];
      s_z += u * W_ih[(64 + d) * 64 + e] + p * W_hh[(64 + d) * 64 + e];
      i_n += u * W_ih[(128 + d) * 64 + e];
      h_n += p * W_hh[(128 + d) * 64 + e];
    }
    const float rg = 1.f / (1.f + __expf(-s_r));
    const float zg = 1.f / (1.f + __expf(-s_z));
    const float ng = tanhf(i_n + rg * h_n);
    const float hv = (1.f - zg) * ng + zg * sp;
    const float mn = wsum64(hv) * (1.f / 64.f);
    const float dv = hv - mn;
    const float vr = wsum64(dv * dv) * (1.f / 64.f);
    const float rs = rsqrtf(vr + 1e-5f);
    const float mld = dv * rs * ln_mlp_g[d] + ln_mlp_b[d];
    __syncthreads();
    t0[d] = mld;
    __syncthreads();
    float h0 = b1[d], h1 = b1[64 + d];
#pragma unroll
    for (int e = 0; e < 64; ++e) {
      const float m = t0[e];
      h0 += m * W1[d * 64 + e];
      h1 += m * W1[(64 + d) * 64 + e];
    }
    hh[d] = fmaxf(h0, 0.f);
    hh[64 + d] = fmaxf(h1, 0.f);
    __syncthreads();
    float o = hv + b2[d];
#pragma unroll
    for (int j = 0; j < 128; ++j) o += hh[j] * W2[d * 128 + j];
    slot = o;
  }

  if (mode == 2) {
    out[bs * 64 + d] = slot;
    return;
  }
  slots[bs * 64 + d] = slot;

  // tail: LN_slot -> q -> gqk (scale & ln_in_g folded), sgq, cb
  const float mn = wsum64(slot) * (1.f / 64.f);
  const float dv = slot - mn;
  const float vr = wsum64(dv * dv) * (1.f / 64.f);
  const float rs = rsqrtf(vr + 1e-5f);
  const float sln = dv * rs * ln_slot_g[d] + ln_slot_b[d];
  __syncthreads();
  t0[d] = sln;
  __syncthreads();
  float qv = 0.f;
#pragma unroll
  for (int e = 0; e < 64; ++e) qv += t0[e] * Wq[d * 64 + e];
  __syncthreads();
  t1[d] = qv;
  __syncthreads();
  float qe = 0.f;
#pragma unroll
  for (int dd = 0; dd < 64; ++dd) qe += t1[dd] * Wk[dd * 64 + d];
  qe *= 0.125f;  // scale = D^-0.5
  const float gq = ln_in_g[d] * qe;
  gqk[(b * 8 + s) * 64 + d] = gq;
  const float sg = wsum64(gq);
  const float cb = wsum64(ln_in_b[d] * qe);
  if (d == 0) {
    sc[(b * 8 + s) * 2 + 0] = sg;
    sc[(b * 8 + s) * 2 + 1] = cb;
  }
  ACC[(b * 8 + s) * 64 + d] = 0.f;
  if (d == 0) Zg[b * 8 + s] = 0.f;
}

// ---------------------------------------------------------------------------
// Main kernel: 1920 blocks (120/batch) x 256 threads. SINGLE-PASS streaming,
// NO barriers in the main loop. Lane = (rw = lane>>3 row-in-octet,
// co = lane&7 column octet): owns cols [co*4..co*4+3] and [32+co*4..+3] of
// its row — both float4 loads perfectly coalesced per wave.
//   dot      : 7 logit partials vs LDS-broadcast gqk (conflict-free)
//   reduce   : 3-step shfl_xor over the 8-lane octet (9 values)
//   softmax  : per-lane on reduced values (x8 replicated, /8 at flush)
//   outer    : acc[7][8] += p*rstd * x  — from the registers holding x
// amdgpu_waves_per_eu(4,4): pins 4 waves/EU -> 128-VGPR budget, so the
// ~94-reg live set (acc 56 + prefetch 16 + softmax temps) does NOT spill
// (R6: compiler targeted 64 VGPRs -> 788 MB scratch traffic).
// Pass loop kept rolled (unroll 1) so the unroller can't hoist extra
// prefetch pairs past the 128-reg budget.
// ---------------------------------------------------------------------------
__global__ __launch_bounds__(256)
__attribute__((amdgpu_waves_per_eu(4, 4))) void k_main(
    const float* __restrict__ x,
    const float* __restrict__ gqk,  // [B][8][64]
    const float* __restrict__ sc,   // [B][8][2]
    float* __restrict__ ACC, float* __restrict__ Zg)
{
  __shared__ __align__(16) float qbs[512];       // 2 KB
  __shared__ __align__(16) float scr[4 * 7 * 64];  // 7 KB
  __shared__ float scs[16];

  const int t = threadIdx.x;
  const int lane = t & 63;
  const int w = t >> 6;
  const int rw = lane >> 3;  // row within 8-row wave pass
  const int co = lane & 7;   // column octet
  const int b = blockIdx.x / BPB;
  const int kb = blockIdx.x % BPB;

  qbs[t] = gqk[b * 512 + t];
  qbs[256 + t] = gqk[b * 512 + 256 + t];
  if (t < 16) scs[t] = sc[b * 16 + t];
  __syncthreads();

  float acc[7][8];
#pragma unroll
  for (int s = 0; s < 7; ++s)
#pragma unroll
    for (int j = 0; j < 8; ++j) acc[s][j] = 0.f;
  float zac[7] = {0, 0, 0, 0, 0, 0, 0};

  // this thread's stream: row = base + ps*32, cols co*4 and 32+co*4
  const float* xp =
      x + ((size_t)b * NN + kb * ROWS_PB + w * 8 + rw) * 64 + co * 4;

  float4 a0 = *reinterpret_cast<const float4*>(xp);
  float4 a1 = *reinterpret_cast<const float4*>(xp + 32);

#pragma unroll 1
  for (int ps = 0; ps < PASSES; ++ps) {
    // prefetch next pass (1-deep: load->use distance = one full pass)
    float4 n0 = a0, n1 = a1;
    if (ps + 1 < PASSES) {
      const float* xn = xp + (size_t)(ps + 1) * 32 * 64;
      n0 = *reinterpret_cast<const float4*>(xn);
      n1 = *reinterpret_cast<const float4*>(xn + 32);
    }

    // ---- dot + LN stats ----
    float lg[7];
    float sum = a0.x + a0.y + a0.z + a0.w + a1.x + a1.y + a1.z + a1.w;
    float sq = fmaf(a0.x, a0.x, fmaf(a0.y, a0.y, fmaf(a0.z, a0.z,
               fmaf(a0.w, a0.w, fmaf(a1.x, a1.x, fmaf(a1.y, a1.y,
               fmaf(a1.z, a1.z, a1.w * a1.w)))))));
#pragma unroll
    for (int s = 0; s < 7; ++s) {
      const float4 g0 = *reinterpret_cast<const float4*>(&qbs[s * 64 + co * 4]);
      const float4 g1 =
          *reinterpret_cast<const float4*>(&qbs[s * 64 + 32 + co * 4]);
      lg[s] = fmaf(a0.x, g0.x, fmaf(a0.y, g0.y, fmaf(a0.z, g0.z,
              fmaf(a0.w, g0.w, fmaf(a1.x, g1.x, fmaf(a1.y, g1.y,
              fmaf(a1.z, g1.z, a1.w * g1.w)))))));
    }
    // ---- 3-step octet reduce (offsets 1,2,4 stay in the 8-lane group) ----
#pragma unroll
    for (int off = 1; off <= 4; off <<= 1) {
      sum += __shfl_xor(sum, off);
      sq += __shfl_xor(sq, off);
#pragma unroll
      for (int s = 0; s < 7; ++s) lg[s] += __shfl_xor(lg[s], off);
    }
    // ---- softmax (per-lane, replicated across octet) ----
    const float mean = sum * (1.f / 64.f);
    const float var = sq * (1.f / 64.f) - mean * mean;
    const float rstd = rsqrtf(var + 1e-5f);
    const float rm = rstd * mean;
    float mx = -1e30f;
#pragma unroll
    for (int s = 0; s < 7; ++s) {
      lg[s] = rstd * lg[s] - rm * scs[s * 2] + scs[s * 2 + 1];
      mx = fmaxf(mx, lg[s]);
    }
    float se = 0.f;
#pragma unroll
    for (int s = 0; s < 7; ++s) {
      lg[s] = __expf(lg[s] - mx);
      se += lg[s];
    }
    const float inv = 1.f / se;
    // ---- outer product into persistent registers ----
#pragma unroll
    for (int s = 0; s < 7; ++s) {
      const float p = lg[s] * inv + 1e-8f;
      const float pr = p * rstd;
      zac[s] += p;  // 8x octet-replicated; corrected at flush
      acc[s][0] = fmaf(pr, a0.x, acc[s][0]);
      acc[s][1] = fmaf(pr, a0.y, acc[s][1]);
      acc[s][2] = fmaf(pr, a0.z, acc[s][2]);
      acc[s][3] = fmaf(pr, a0.w, acc[s][3]);
      acc[s][4] = fmaf(pr, a1.x, acc[s][4]);
      acc[s][5] = fmaf(pr, a1.y, acc[s][5]);
      acc[s][6] = fmaf(pr, a1.z, acc[s][6]);
      acc[s][7] = fmaf(pr, a1.w, acc[s][7]);
    }
    a0 = n0;
    a1 = n1;
  }

  // ---- flush (once per block) ----
  // sum across the 8 row-octets of the wave (lanes with same co)
#pragma unroll
  for (int s = 0; s < 7; ++s)
#pragma unroll
    for (int j = 0; j < 8; ++j) {
      acc[s][j] += __shfl_xor(acc[s][j], 8);
      acc[s][j] += __shfl_xor(acc[s][j], 16);
      acc[s][j] += __shfl_xor(acc[s][j], 32);
    }
  if (rw == 0) {  // lanes 0..7: co = lane
#pragma unroll
    for (int s = 0; s < 7; ++s) {
      const float4 v0 = {acc[s][0], acc[s][1], acc[s][2], acc[s][3]};
      const float4 v1 = {acc[s][4], acc[s][5], acc[s][6], acc[s][7]};
      *reinterpret_cast<float4*>(&scr[(w * 7 + s) * 64 + co * 4]) = v0;
      *reinterpret_cast<float4*>(&scr[(w * 7 + s) * 64 + 32 + co * 4]) = v1;
    }
  }
  __syncthreads();
  {
    const int d = lane;
    float v0 = scr[(0 * 7 + w) * 64 + d] + scr[(1 * 7 + w) * 64 + d] +
               scr[(2 * 7 + w) * 64 + d] + scr[(3 * 7 + w) * 64 + d];
    atomicAdd(&ACC[(b * 8 + w) * 64 + d], v0);
    if (w < 3) {
      float v1 = scr[(0 * 7 + w + 4) * 64 + d] + scr[(1 * 7 + w + 4) * 64 + d] +
                 scr[(2 * 7 + w + 4) * 64 + d] + scr[(3 * 7 + w + 4) * 64 + d];
      atomicAdd(&ACC[(b * 8 + w + 4) * 64 + d], v1);
    }
  }
  float zv = 0.f;
#pragma unroll
  for (int s = 0; s < 7; ++s) {
    const float z = wsum64(zac[s]) * 0.125f;  // undo 8x octet replication
    if (lane == s) zv = z;
  }
  if (lane < 7) atomicAdd(&Zg[b * 8 + lane], zv);
}

extern "C" void kernel_launch(void* const* d_in, const int* in_sizes, int n_in,
                              void* d_out, int out_size, void* d_ws,
                              size_t ws_size, hipStream_t stream) {
  const float* inputs     = (const float*)d_in[0];
  const float* slots_init = (const float*)d_in[1];
  const float* slots_mu   = (const float*)d_in[2];
  const float* slots_lsig = (const float*)d_in[3];
  const float* ln_in_g    = (const float*)d_in[4];
  const float* ln_in_b    = (const float*)d_in[5];
  const float* ln_slot_g  = (const float*)d_in[6];
  const float* ln_slot_b  = (const float*)d_in[7];
  const float* ln_mlp_g   = (const float*)d_in[8];
  const float* ln_mlp_b   = (const float*)d_in[9];
  const float* Wq   = (const float*)d_in[10];
  const float* Wk   = (const float*)d_in[11];
  const float* Wv   = (const float*)d_in[12];
  const float* W_ih = (const float*)d_in[13];
  const float* W_hh = (const float*)d_in[14];
  const float* b_ih = (const float*)d_in[15];
  const float* b_hh = (const float*)d_in[16];
  const float* W1   = (const float*)d_in[17];
  const float* b1   = (const float*)d_in[18];
  const float* W2   = (const float*)d_in[19];
  const float* b2   = (const float*)d_in[20];

  float* ws    = (float*)d_ws;
  float* slots = ws;            // B*S*64 = 7168
  float* gqk   = ws + 7168;     // B*8*64 = 8192
  float* sc    = gqk + 8192;    // B*8*2  = 256
  float* ACC   = sc + 256;      // B*8*64 = 8192
  float* Zg    = ACC + 8192;    // B*8    = 128

  float* out = (float*)d_out;

#define SLOT_ARGS                                                          \
  slots_init, slots_mu, slots_lsig, ln_slot_g, ln_slot_b, ln_mlp_g,        \
      ln_mlp_b, ln_in_g, ln_in_b, Wq, Wk, Wv, W_ih, W_hh, b_ih, b_hh, W1,  \
      b1, W2, b2, slots, gqk, sc, ACC, Zg, out

  k_slot<<<112, 64, 0, stream>>>(0, SLOT_ARGS);
  for (int it = 0; it < 3; ++it) {
    k_main<<<BB * BPB, 256, 0, stream>>>(inputs, gqk, sc, ACC, Zg);
    k_slot<<<112, 64, 0, stream>>>(it == 2 ? 2 : 1, SLOT_ARGS);
  }
#undef SLOT_ARGS
}

// Round 8
// 331.073 us; speedup vs baseline: 3.7735x; 2.5050x over previous
//
#include <hip/hip_runtime.h>

#define BB 16
#define NN 38400
#define SS 7
#define BPB 120                 // blocks per batch
#define ROWS_PB (NN / BPB)      // 320 rows per block
#define PASSES (ROWS_PB / 16)   // 20 passes: 4 waves x 4 rows per pass

__device__ __forceinline__ float wsum64(float v) {
#pragma unroll
  for (int off = 32; off > 0; off >>= 1) v += __shfl_xor(v, off);
  return v;
}

// ---------------------------------------------------------------------------
// Slot-side kernel: 112 blocks (one per (b,s)), 64 threads (lane = d).
// mode 0: init slots; mode 1: GRU+MLP update; mode 2: update + write out.
// ACCM is recovered from ACC: sum_n p*rstd*mean = (1/64) * sum_d ACC[s][d].
// ---------------------------------------------------------------------------
__global__ __launch_bounds__(64) void k_slot(
    int mode,
    const float* __restrict__ slots_init, const float* __restrict__ mu,
    const float* __restrict__ lsig,
    const float* __restrict__ ln_slot_g, const float* __restrict__ ln_slot_b,
    const float* __restrict__ ln_mlp_g, const float* __restrict__ ln_mlp_b,
    const float* __restrict__ ln_in_g, const float* __restrict__ ln_in_b,
    const float* __restrict__ Wq, const float* __restrict__ Wk,
    const float* __restrict__ Wv,
    const float* __restrict__ W_ih, const float* __restrict__ W_hh,
    const float* __restrict__ b_ih, const float* __restrict__ b_hh,
    const float* __restrict__ W1, const float* __restrict__ b1,
    const float* __restrict__ W2, const float* __restrict__ b2,
    float* __restrict__ slots, float* __restrict__ gqk,
    float* __restrict__ sc,
    float* __restrict__ ACC, float* __restrict__ Zg,
    float* __restrict__ out)
{
  const int bs = blockIdx.x;
  const int b = bs / SS, s = bs % SS;
  const int d = threadIdx.x;
  __shared__ float t0[64], t1[64], hh[128];

  float slot;
  if (mode == 0) {
    slot = mu[d] + __expf(lsig[d]) * slots_init[bs * 64 + d];
  } else {
    const float zv = Zg[b * 8 + s];
    const float ac = ACC[(b * 8 + s) * 64 + d];
    const float am = wsum64(ac) * (1.f / 64.f);  // = sum_n p*rstd*mean
    const float ubar = (ln_in_g[d] * (ac - am) + ln_in_b[d] * zv) / zv;
    t0[d] = ubar;
    __syncthreads();
    float upd = 0.f;
#pragma unroll
    for (int e = 0; e < 64; ++e) upd += t0[e] * Wv[d * 64 + e];
    const float sp = slots[bs * 64 + d];
    __syncthreads();
    t0[d] = upd;
    t1[d] = sp;
    __syncthreads();
    float s_r = b_ih[d] + b_hh[d];
    float s_z = b_ih[64 + d] + b_hh[64 + d];
    float i_n = b_ih[128 + d];
    float h_n = b_hh[128 + d];
#pragma unroll
    for (int e = 0; e < 64; ++e) {
      const float u = t0[e], p = t1[e];
      s_r += u * W_ih[d * 64 + e] + p * W_hh[d * 64 + e];
      s_z += u * W_ih[(64 + d) * 64 + e] + p * W_hh[(64 + d) * 64 + e];
      i_n += u * W_ih[(128 + d) * 64 + e];
      h_n += p * W_hh[(128 + d) * 64 + e];
    }
    const float rg = 1.f / (1.f + __expf(-s_r));
    const float zg = 1.f / (1.f + __expf(-s_z));
    const float ng = tanhf(i_n + rg * h_n);
    const float hv = (1.f - zg) * ng + zg * sp;
    const float mn = wsum64(hv) * (1.f / 64.f);
    const float dv = hv - mn;
    const float vr = wsum64(dv * dv) * (1.f / 64.f);
    const float rs = rsqrtf(vr + 1e-5f);
    const float mld = dv * rs * ln_mlp_g[d] + ln_mlp_b[d];
    __syncthreads();
    t0[d] = mld;
    __syncthreads();
    float h0 = b1[d], h1 = b1[64 + d];
#pragma unroll
    for (int e = 0; e < 64; ++e) {
      const float m = t0[e];
      h0 += m * W1[d * 64 + e];
      h1 += m * W1[(64 + d) * 64 + e];
    }
    hh[d] = fmaxf(h0, 0.f);
    hh[64 + d] = fmaxf(h1, 0.f);
    __syncthreads();
    float o = hv + b2[d];
#pragma unroll
    for (int j = 0; j < 128; ++j) o += hh[j] * W2[d * 128 + j];
    slot = o;
  }

  if (mode == 2) {
    out[bs * 64 + d] = slot;
    return;
  }
  slots[bs * 64 + d] = slot;

  // tail: LN_slot -> q -> gqk (scale & ln_in_g folded), sgq, cb
  const float mn = wsum64(slot) * (1.f / 64.f);
  const float dv = slot - mn;
  const float vr = wsum64(dv * dv) * (1.f / 64.f);
  const float rs = rsqrtf(vr + 1e-5f);
  const float sln = dv * rs * ln_slot_g[d] + ln_slot_b[d];
  __syncthreads();
  t0[d] = sln;
  __syncthreads();
  float qv = 0.f;
#pragma unroll
  for (int e = 0; e < 64; ++e) qv += t0[e] * Wq[d * 64 + e];
  __syncthreads();
  t1[d] = qv;
  __syncthreads();
  float qe = 0.f;
#pragma unroll
  for (int dd = 0; dd < 64; ++dd) qe += t1[dd] * Wk[dd * 64 + d];
  qe *= 0.125f;  // scale = D^-0.5
  const float gq = ln_in_g[d] * qe;
  gqk[(b * 8 + s) * 64 + d] = gq;
  const float sg = wsum64(gq);
  const float cb = wsum64(ln_in_b[d] * qe);
  if (d == 0) {
    sc[(b * 8 + s) * 2 + 0] = sg;
    sc[(b * 8 + s) * 2 + 1] = cb;
  }
  ACC[(b * 8 + s) * 64 + d] = 0.f;
  if (d == 0) Zg[b * 8 + s] = 0.f;
}

// ---------------------------------------------------------------------------
// Main kernel: 1920 blocks (120/batch) x 256 threads. Single-pass streaming,
// no barriers in the loop. 16 lanes per row: lane = (rw = lane>>4 row,
// co = lane&15 col-quad) — one float4 per lane per pass; wave covers 4 rows
// x 64 cols = 1KB contiguous (perfectly coalesced).
//   dot      : 7 logit partials vs LDS-broadcast gqk
//   reduce   : 4-step shfl_xor over the 16-lane group (9 values)
//   softmax  : per-lane (x16 replicated, /16 at flush)
//   outer    : acc[7][4] += p*rstd * x  (registers only)
// Per-lane persistent state ~58 VGPRs — fits the compiler's 64-VGPR target
// for 256-thread blocks (R6/R7 lesson: exceeding it => 300-800 MB scratch).
// No explicit prefetch: 8 waves/SIMD of TLP hide the load latency.
// ---------------------------------------------------------------------------
__global__ __launch_bounds__(256) void k_main(
    const float* __restrict__ x,
    const float* __restrict__ gqk,  // [B][8][64]
    const float* __restrict__ sc,   // [B][8][2]
    float* __restrict__ ACC, float* __restrict__ Zg)
{
  __shared__ __align__(16) float qbs[512];         // 2 KB
  __shared__ __align__(16) float scr[4 * 7 * 64];  // 7 KB
  __shared__ float scs[16];

  const int t = threadIdx.x;
  const int lane = t & 63;
  const int w = t >> 6;
  const int rw = lane >> 4;  // row within 4-row pass
  const int co = lane & 15;  // column quad
  const int b = blockIdx.x / BPB;
  const int kb = blockIdx.x % BPB;

  qbs[t] = gqk[b * 512 + t];
  qbs[256 + t] = gqk[b * 512 + 256 + t];
  if (t < 16) scs[t] = sc[b * 16 + t];
  __syncthreads();

  float acc[7][4];
#pragma unroll
  for (int s = 0; s < 7; ++s)
#pragma unroll
    for (int j = 0; j < 4; ++j) acc[s][j] = 0.f;
  float zac[7] = {0, 0, 0, 0, 0, 0, 0};

  // wave w owns 80 consecutive rows: 20 passes x 4 rows
  const float* xp =
      x + ((size_t)b * NN + kb * ROWS_PB + w * (ROWS_PB / 4) + rw) * 64 +
      co * 4;

#pragma unroll 1
  for (int ps = 0; ps < PASSES; ++ps) {
    const float4 a = *reinterpret_cast<const float4*>(xp + (size_t)ps * 256);

    // ---- dot + LN stats ----
    float lg[7];
    float sum = a.x + a.y + a.z + a.w;
    float sq = fmaf(a.x, a.x, fmaf(a.y, a.y, fmaf(a.z, a.z, a.w * a.w)));
#pragma unroll
    for (int s = 0; s < 7; ++s) {
      const float4 g = *reinterpret_cast<const float4*>(&qbs[s * 64 + co * 4]);
      lg[s] = fmaf(a.x, g.x, fmaf(a.y, g.y, fmaf(a.z, g.z, a.w * g.w)));
    }
    // ---- 4-step reduce over the 16-lane row group ----
#pragma unroll
    for (int off = 1; off <= 8; off <<= 1) {
      sum += __shfl_xor(sum, off);
      sq += __shfl_xor(sq, off);
#pragma unroll
      for (int s = 0; s < 7; ++s) lg[s] += __shfl_xor(lg[s], off);
    }
    // ---- softmax (per-lane, replicated x16) ----
    const float mean = sum * (1.f / 64.f);
    const float var = sq * (1.f / 64.f) - mean * mean;
    const float rstd = rsqrtf(var + 1e-5f);
    const float rm = rstd * mean;
    float mx = -1e30f;
#pragma unroll
    for (int s = 0; s < 7; ++s) {
      lg[s] = rstd * lg[s] - rm * scs[s * 2] + scs[s * 2 + 1];
      mx = fmaxf(mx, lg[s]);
    }
    float se = 0.f;
#pragma unroll
    for (int s = 0; s < 7; ++s) {
      lg[s] = __expf(lg[s] - mx);
      se += lg[s];
    }
    const float inv = 1.f / se;
    // ---- outer product into persistent registers ----
#pragma unroll
    for (int s = 0; s < 7; ++s) {
      const float p = lg[s] * inv + 1e-8f;
      const float pr = p * rstd;
      zac[s] += p;  // x16 replicated; corrected at flush
      acc[s][0] = fmaf(pr, a.x, acc[s][0]);
      acc[s][1] = fmaf(pr, a.y, acc[s][1]);
      acc[s][2] = fmaf(pr, a.z, acc[s][2]);
      acc[s][3] = fmaf(pr, a.w, acc[s][3]);
    }
  }

  // ---- flush (once per block) ----
  // sum the 4 row-groups (lanes with same co across rw)
#pragma unroll
  for (int s = 0; s < 7; ++s)
#pragma unroll
    for (int j = 0; j < 4; ++j) {
      acc[s][j] += __shfl_xor(acc[s][j], 16);
      acc[s][j] += __shfl_xor(acc[s][j], 32);
    }
  if (rw == 0) {  // lanes 0..15: co = lane
#pragma unroll
    for (int s = 0; s < 7; ++s) {
      const float4 v = {acc[s][0], acc[s][1], acc[s][2], acc[s][3]};
      *reinterpret_cast<float4*>(&scr[(w * 7 + s) * 64 + co * 4]) = v;
    }
  }
  __syncthreads();
  {
    const int d = lane;
    float v0 = scr[(0 * 7 + w) * 64 + d] + scr[(1 * 7 + w) * 64 + d] +
               scr[(2 * 7 + w) * 64 + d] + scr[(3 * 7 + w) * 64 + d];
    atomicAdd(&ACC[(b * 8 + w) * 64 + d], v0);
    if (w < 3) {
      float v1 = scr[(0 * 7 + w + 4) * 64 + d] + scr[(1 * 7 + w + 4) * 64 + d] +
                 scr[(2 * 7 + w + 4) * 64 + d] + scr[(3 * 7 + w + 4) * 64 + d];
      atomicAdd(&ACC[(b * 8 + w + 4) * 64 + d], v1);
    }
  }
  float zv = 0.f;
#pragma unroll
  for (int s = 0; s < 7; ++s) {
    const float z = wsum64(zac[s]) * (1.f / 16.f);  // undo x16 replication
    if (lane == s) zv = z;
  }
  if (lane < 7) atomicAdd(&Zg[b * 8 + lane], zv);
}

extern "C" void kernel_launch(void* const* d_in, const int* in_sizes, int n_in,
                              void* d_out, int out_size, void* d_ws,
                              size_t ws_size, hipStream_t stream) {
  const float* inputs     = (const float*)d_in[0];
  const float* slots_init = (const float*)d_in[1];
  const float* slots_mu   = (const float*)d_in[2];
  const float* slots_lsig = (const float*)d_in[3];
  const float* ln_in_g    = (const float*)d_in[4];
  const float* ln_in_b    = (const float*)d_in[5];
  const float* ln_slot_g  = (const float*)d_in[6];
  const float* ln_slot_b  = (const float*)d_in[7];
  const float* ln_mlp_g   = (const float*)d_in[8];
  const float* ln_mlp_b   = (const float*)d_in[9];
  const float* Wq   = (const float*)d_in[10];
  const float* Wk   = (const float*)d_in[11];
  const float* Wv   = (const float*)d_in[12];
  const float* W_ih = (const float*)d_in[13];
  const float* W_hh = (const float*)d_in[14];
  const float* b_ih = (const float*)d_in[15];
  const float* b_hh = (const float*)d_in[16];
  const float* W1   = (const float*)d_in[17];
  const float* b1   = (const float*)d_in[18];
  const float* W2   = (const float*)d_in[19];
  const float* b2   = (const float*)d_in[20];

  float* ws    = (float*)d_ws;
  float* slots = ws;            // B*S*64 = 7168
  float* gqk   = ws + 7168;     // B*8*64 = 8192
  float* sc    = gqk + 8192;    // B*8*2  = 256
  float* ACC   = sc + 256;      // B*8*64 = 8192
  float* Zg    = ACC + 8192;    // B*8    = 128

  float* out = (float*)d_out;

#define SLOT_ARGS                                                          \
  slots_init, slots_mu, slots_lsig, ln_slot_g, ln_slot_b, ln_mlp_g,        \
      ln_mlp_b, ln_in_g, ln_in_b, Wq, Wk, Wv, W_ih, W_hh, b_ih, b_hh, W1,  \
      b1, W2, b2, slots, gqk, sc, ACC, Zg, out

  k_slot<<<112, 64, 0, stream>>>(0, SLOT_ARGS);
  for (int it = 0; it < 3; ++it) {
    k_main<<<BB * BPB, 256, 0, stream>>>(inputs, gqk, sc, ACC, Zg);
    k_slot<<<112, 64, 0, stream>>>(it == 2 ? 2 : 1, SLOT_ARGS);
  }
#undef SLOT_ARGS
}

// Round 9
// 249.454 us; speedup vs baseline: 5.0082x; 1.3272x over previous
//
#include <hip/hip_runtime.h>

#define BB 16
#define NN 38400
#define SS 7
#define BPB 120                // blocks per batch -> grid 1920
#define ROWS_PB 320            // rows per block (4 waves x 80)
#define TILES 5                // 16-row tiles per wave

__device__ __forceinline__ float wsum64(float v) {
#pragma unroll
  for (int off = 32; off > 0; off >>= 1) v += __shfl_xor(v, off);
  return v;
}

// ---------------------------------------------------------------------------
// Slot-side kernel (unchanged, proven): 112 blocks, 64 threads.
// mode 0: init slots; mode 1: GRU+MLP update; mode 2: update + write out.
// ACCM recovered from ACC: sum_n p*rstd*mean = (1/64) * sum_d ACC[s][d].
// ---------------------------------------------------------------------------
__global__ __launch_bounds__(64) void k_slot(
    int mode,
    const float* __restrict__ slots_init, const float* __restrict__ mu,
    const float* __restrict__ lsig,
    const float* __restrict__ ln_slot_g, const float* __restrict__ ln_slot_b,
    const float* __restrict__ ln_mlp_g, const float* __restrict__ ln_mlp_b,
    const float* __restrict__ ln_in_g, const float* __restrict__ ln_in_b,
    const float* __restrict__ Wq, const float* __restrict__ Wk,
    const float* __restrict__ Wv,
    const float* __restrict__ W_ih, const float* __restrict__ W_hh,
    const float* __restrict__ b_ih, const float* __restrict__ b_hh,
    const float* __restrict__ W1, const float* __restrict__ b1,
    const float* __restrict__ W2, const float* __restrict__ b2,
    float* __restrict__ slots, float* __restrict__ gqk,
    float* __restrict__ sc,
    float* __restrict__ ACC, float* __restrict__ Zg,
    float* __restrict__ out)
{
  const int bs = blockIdx.x;
  const int b = bs / SS, s = bs % SS;
  const int d = threadIdx.x;
  __shared__ float t0[64], t1[64], hh[128];

  float slot;
  if (mode == 0) {
    slot = mu[d] + __expf(lsig[d]) * slots_init[bs * 64 + d];
  } else {
    const float zv = Zg[b * 8 + s];
    const float ac = ACC[(b * 8 + s) * 64 + d];
    const float am = wsum64(ac) * (1.f / 64.f);
    const float ubar = (ln_in_g[d] * (ac - am) + ln_in_b[d] * zv) / zv;
    t0[d] = ubar;
    __syncthreads();
    float upd = 0.f;
#pragma unroll
    for (int e = 0; e < 64; ++e) upd += t0[e] * Wv[d * 64 + e];
    const float sp = slots[bs * 64 + d];
    __syncthreads();
    t0[d] = upd;
    t1[d] = sp;
    __syncthreads();
    float s_r = b_ih[d] + b_hh[d];
    float s_z = b_ih[64 + d] + b_hh[64 + d];
    float i_n = b_ih[128 + d];
    float h_n = b_hh[128 + d];
#pragma unroll
    for (int e = 0; e < 64; ++e) {
      const float u = t0[e], p = t1[e];
      s_r += u * W_ih[d * 64 + e] + p * W_hh[d * 64 + e];
      s_z += u * W_ih[(64 + d) * 64 + e] + p * W_hh[(64 + d) * 64 + e];
      i_n += u * W_ih[(128 + d) * 64 + e];
      h_n += p * W_hh[(128 + d) * 64 + e];
    }
    const float rg = 1.f / (1.f + __expf(-s_r));
    const float zg = 1.f / (1.f + __expf(-s_z));
    const float ng = tanhf(i_n + rg * h_n);
    const float hv = (1.f - zg) * ng + zg * sp;
    const float mn = wsum64(hv) * (1.f / 64.f);
    const float dv = hv - mn;
    const float vr = wsum64(dv * dv) * (1.f / 64.f);
    const float rs = rsqrtf(vr + 1e-5f);
    const float mld = dv * rs * ln_mlp_g[d] + ln_mlp_b[d];
    __syncthreads();
    t0[d] = mld;
    __syncthreads();
    float h0 = b1[d], h1 = b1[64 + d];
#pragma unroll
    for (int e = 0; e < 64; ++e) {
      const float m = t0[e];
      h0 += m * W1[d * 64 + e];
      h1 += m * W1[(64 + d) * 64 + e];
    }
    hh[d] = fmaxf(h0, 0.f);
    hh[64 + d] = fmaxf(h1, 0.f);
    __syncthreads();
    float o = hv + b2[d];
#pragma unroll
    for (int j = 0; j < 128; ++j) o += hh[j] * W2[d * 128 + j];
    slot = o;
  }

  if (mode == 2) {
    out[bs * 64 + d] = slot;
    return;
  }
  slots[bs * 64 + d] = slot;

  const float mn = wsum64(slot) * (1.f / 64.f);
  const float dv = slot - mn;
  const float vr = wsum64(dv * dv) * (1.f / 64.f);
  const float rs = rsqrtf(vr + 1e-5f);
  const float sln = dv * rs * ln_slot_g[d] + ln_slot_b[d];
  __syncthreads();
  t0[d] = sln;
  __syncthreads();
  float qv = 0.f;
#pragma unroll
  for (int e = 0; e < 64; ++e) qv += t0[e] * Wq[d * 64 + e];
  __syncthreads();
  t1[d] = qv;
  __syncthreads();
  float qe = 0.f;
#pragma unroll
  for (int dd = 0; dd < 64; ++dd) qe += t1[dd] * Wk[dd * 64 + d];
  qe *= 0.125f;  // scale = D^-0.5
  const float gq = ln_in_g[d] * qe;
  gqk[(b * 8 + s) * 64 + d] = gq;
  const float sg = wsum64(gq);
  const float cb = wsum64(ln_in_b[d] * qe);
  if (d == 0) {
    sc[(b * 8 + s) * 2 + 0] = sg;
    sc[(b * 8 + s) * 2 + 1] = cb;
  }
  ACC[(b * 8 + s) * 64 + d] = 0.f;
  if (d == 0) Zg[b * 8 + s] = 0.f;
}

// ---------------------------------------------------------------------------
// Main kernel: 1920 blocks x 256 threads. WAVE-PRIVATE 16-row tiles, no
// block barriers in the loop (intra-wave LDS ordering via compiler lgkmcnt):
//   stage: 16 rows coalesced float4 -> LDS slice (row stride 68 floats)
//   P1   : quad-per-row (64 quads = 64 lanes): 4 b128 LDS reads, 7 dots +
//          LN stats, 2-step shfl reduce, softmax (x4 replicated only),
//          q==0 writes p*rstd[7] to pa slice (row stride 12)
//   P2   : lane=(rg=lane>>4, d4=lane&15): 4 rows {rg+4i}: b128 x read +
//          2 broadcast pa reads + 28 fma into persistent acc[7][4]
// ~1080 thread-instrs/row vs R8's ~2450 (the x16 softmax/reduce replication
// was the bottleneck). Regs: acc 28 + zac 7 + peak temps ~25 <= 64 target.
// ---------------------------------------------------------------------------
__global__ __launch_bounds__(256) void k_main(
    const float* __restrict__ x,
    const float* __restrict__ gqk,  // [B][8][64]
    const float* __restrict__ sc,   // [B][8][2]
    float* __restrict__ ACC, float* __restrict__ Zg)
{
  __shared__ __align__(16) float xs[4][16 * 68];   // 17408 B
  __shared__ __align__(16) float pas[4][16 * 12];  // 3072 B
  __shared__ __align__(16) float qbs[512];         // 2048 B
  __shared__ __align__(16) float scr[4 * 7 * 64];  // 7168 B
  __shared__ float scs[16];

  const int t = threadIdx.x;
  const int lane = t & 63;
  const int w = t >> 6;
  const int b = blockIdx.x / BPB;
  const int kb = blockIdx.x % BPB;

  qbs[t] = gqk[b * 512 + t];
  qbs[256 + t] = gqk[b * 512 + 256 + t];
  if (t < 16) scs[t] = sc[b * 16 + t];
  __syncthreads();  // qbs/scs ready (only barrier before flush)

  float* xw = xs[w];
  float* paw = pas[w];

  const int r1 = lane >> 2, q1 = lane & 3;   // P1: row, quad-lane
  const int rg = lane >> 4, d4 = lane & 15;  // P2/stage: row-residue, chunk

  float acc[7][4];
#pragma unroll
  for (int s = 0; s < 7; ++s)
#pragma unroll
    for (int j = 0; j < 4; ++j) acc[s][j] = 0.f;
  float zac[7] = {0, 0, 0, 0, 0, 0, 0};

  // wave w owns 80 consecutive rows: 5 tiles x 16 rows
  const float4* xg = reinterpret_cast<const float4*>(x) +
                     ((size_t)b * NN + (size_t)kb * ROWS_PB + w * 80) * 16;

#pragma unroll 1
  for (int tl = 0; tl < TILES; ++tl) {
    // ---- stage: 16 rows, fully coalesced (wave covers 4 rows/instr) ----
    {
      const float4* src = xg + (size_t)tl * 256;
#pragma unroll
      for (int i = 0; i < 4; ++i) {
        const int rl = rg + 4 * i;
        const float4 v = src[rl * 16 + d4];
        *reinterpret_cast<float4*>(&xw[rl * 68 + d4 * 4]) = v;
      }
    }

    // ---- P1: quad-per-row from LDS ----
    {
      float lg[7] = {0, 0, 0, 0, 0, 0, 0};
      float sum = 0.f, sq = 0.f;
#pragma unroll
      for (int j = 0; j < 4; ++j) {
        const float4 v = *reinterpret_cast<const float4*>(
            &xw[r1 * 68 + (q1 * 4 + j) * 4]);
        sum += v.x + v.y + v.z + v.w;
        sq = fmaf(v.x, v.x, fmaf(v.y, v.y, fmaf(v.z, v.z, fmaf(v.w, v.w, sq))));
#pragma unroll
        for (int s = 0; s < 7; ++s) {
          const float4 g = *reinterpret_cast<const float4*>(
              &qbs[s * 64 + q1 * 16 + j * 4]);
          lg[s] = fmaf(v.x, g.x,
                       fmaf(v.y, g.y, fmaf(v.z, g.z, fmaf(v.w, g.w, lg[s]))));
        }
      }
      // 2-step quad reduce (offsets 1,2 stay within the 4-lane group)
#pragma unroll
      for (int off = 1; off <= 2; off <<= 1) {
        sum += __shfl_xor(sum, off);
        sq += __shfl_xor(sq, off);
#pragma unroll
        for (int s = 0; s < 7; ++s) lg[s] += __shfl_xor(lg[s], off);
      }
      const float mean = sum * (1.f / 64.f);
      const float var = sq * (1.f / 64.f) - mean * mean;
      const float rstd = rsqrtf(var + 1e-5f);
      const float rm = rstd * mean;
      float mx = -1e30f;
#pragma unroll
      for (int s = 0; s < 7; ++s) {
        lg[s] = rstd * lg[s] - rm * scs[s * 2] + scs[s * 2 + 1];
        mx = fmaxf(mx, lg[s]);
      }
      float se = 0.f;
#pragma unroll
      for (int s = 0; s < 7; ++s) {
        lg[s] = __expf(lg[s] - mx);
        se += lg[s];
      }
      const float inv = 1.f / se;
      float pr[7];
#pragma unroll
      for (int s = 0; s < 7; ++s) {
        const float p = lg[s] * inv + 1e-8f;
        pr[s] = p * rstd;
        zac[s] += p;  // x4 quad-replicated; /4 at flush
      }
      if (q1 == 0) {
        const float4 w1 = {pr[0], pr[1], pr[2], pr[3]};
        const float4 w2 = {pr[4], pr[5], pr[6], 0.f};
        *reinterpret_cast<float4*>(&paw[r1 * 12]) = w1;
        *reinterpret_cast<float4*>(&paw[r1 * 12 + 4]) = w2;
      }
    }

    // ---- P2: outer product from LDS into persistent registers ----
#pragma unroll
    for (int i = 0; i < 4; ++i) {
      const int rl = rg + 4 * i;
      const float4 xv =
          *reinterpret_cast<const float4*>(&xw[rl * 68 + d4 * 4]);
      const float4 pA = *reinterpret_cast<const float4*>(&paw[rl * 12]);
      const float4 pB = *reinterpret_cast<const float4*>(&paw[rl * 12 + 4]);
      acc[0][0] = fmaf(pA.x, xv.x, acc[0][0]);
      acc[0][1] = fmaf(pA.x, xv.y, acc[0][1]);
      acc[0][2] = fmaf(pA.x, xv.z, acc[0][2]);
      acc[0][3] = fmaf(pA.x, xv.w, acc[0][3]);
      acc[1][0] = fmaf(pA.y, xv.x, acc[1][0]);
      acc[1][1] = fmaf(pA.y, xv.y, acc[1][1]);
      acc[1][2] = fmaf(pA.y, xv.z, acc[1][2]);
      acc[1][3] = fmaf(pA.y, xv.w, acc[1][3]);
      acc[2][0] = fmaf(pA.z, xv.x, acc[2][0]);
      acc[2][1] = fmaf(pA.z, xv.y, acc[2][1]);
      acc[2][2] = fmaf(pA.z, xv.z, acc[2][2]);
      acc[2][3] = fmaf(pA.z, xv.w, acc[2][3]);
      acc[3][0] = fmaf(pA.w, xv.x, acc[3][0]);
      acc[3][1] = fmaf(pA.w, xv.y, acc[3][1]);
      acc[3][2] = fmaf(pA.w, xv.z, acc[3][2]);
      acc[3][3] = fmaf(pA.w, xv.w, acc[3][3]);
      acc[4][0] = fmaf(pB.x, xv.x, acc[4][0]);
      acc[4][1] = fmaf(pB.x, xv.y, acc[4][1]);
      acc[4][2] = fmaf(pB.x, xv.z, acc[4][2]);
      acc[4][3] = fmaf(pB.x, xv.w, acc[4][3]);
      acc[5][0] = fmaf(pB.y, xv.x, acc[5][0]);
      acc[5][1] = fmaf(pB.y, xv.y, acc[5][1]);
      acc[5][2] = fmaf(pB.y, xv.z, acc[5][2]);
      acc[5][3] = fmaf(pB.y, xv.w, acc[5][3]);
      acc[6][0] = fmaf(pB.z, xv.x, acc[6][0]);
      acc[6][1] = fmaf(pB.z, xv.y, acc[6][1]);
      acc[6][2] = fmaf(pB.z, xv.z, acc[6][2]);
      acc[6][3] = fmaf(pB.z, xv.w, acc[6][3]);
    }
  }

  // ---- flush (once per block) ----
  // combine the 4 row-residues (lanes with same d4 across rg)
#pragma unroll
  for (int s = 0; s < 7; ++s)
#pragma unroll
    for (int j = 0; j < 4; ++j) {
      acc[s][j] += __shfl_xor(acc[s][j], 16);
      acc[s][j] += __shfl_xor(acc[s][j], 32);
    }
  if (rg == 0) {  // lanes 0..15: d4 = lane
#pragma unroll
    for (int s = 0; s < 7; ++s) {
      const float4 v = {acc[s][0], acc[s][1], acc[s][2], acc[s][3]};
      *reinterpret_cast<float4*>(&scr[((w * 7 + s) * 16 + d4) * 4]) = v;
    }
  }
  __syncthreads();
  {
    const int d = lane;
    float v0 = scr[((0 * 7 + w) * 16 + (d >> 2)) * 4 + (d & 3)] +
               scr[((1 * 7 + w) * 16 + (d >> 2)) * 4 + (d & 3)] +
               scr[((2 * 7 + w) * 16 + (d >> 2)) * 4 + (d & 3)] +
               scr[((3 * 7 + w) * 16 + (d >> 2)) * 4 + (d & 3)];
    atomicAdd(&ACC[(b * 8 + w) * 64 + d], v0);
    if (w < 3) {
      float v1 = scr[((0 * 7 + w + 4) * 16 + (d >> 2)) * 4 + (d & 3)] +
                 scr[((1 * 7 + w + 4) * 16 + (d >> 2)) * 4 + (d & 3)] +
                 scr[((2 * 7 + w + 4) * 16 + (d >> 2)) * 4 + (d & 3)] +
                 scr[((3 * 7 + w + 4) * 16 + (d >> 2)) * 4 + (d & 3)];
      atomicAdd(&ACC[(b * 8 + w + 4) * 64 + d], v1);
    }
  }
  float zv = 0.f;
#pragma unroll
  for (int s = 0; s < 7; ++s) {
    const float z = wsum64(zac[s]) * 0.25f;  // undo x4 quad replication
    if (lane == s) zv = z;
  }
  if (lane < 7) atomicAdd(&Zg[b * 8 + lane], zv);
}

extern "C" void kernel_launch(void* const* d_in, const int* in_sizes, int n_in,
                              void* d_out, int out_size, void* d_ws,
                              size_t ws_size, hipStream_t stream) {
  const float* inputs     = (const float*)d_in[0];
  const float* slots_init = (const float*)d_in[1];
  const float* slots_mu   = (const float*)d_in[2];
  const float* slots_lsig = (const float*)d_in[3];
  const float* ln_in_g    = (const float*)d_in[4];
  const float* ln_in_b    = (const float*)d_in[5];
  const float* ln_slot_g  = (const float*)d_in[6];
  const float* ln_slot_b  = (const float*)d_in[7];
  const float* ln_mlp_g   = (const float*)d_in[8];
  const float* ln_mlp_b   = (const float*)d_in[9];
  const float* Wq   = (const float*)d_in[10];
  const float* Wk   = (const float*)d_in[11];
  const float* Wv   = (const float*)d_in[12];
  const float* W_ih = (const float*)d_in[13];
  const float* W_hh = (const float*)d_in[14];
  const float* b_ih = (const float*)d_in[15];
  const float* b_hh = (const float*)d_in[16];
  const float* W1   = (const float*)d_in[17];
  const float* b1   = (const float*)d_in[18];
  const float* W2   = (const float*)d_in[19];
  const float* b2   = (const float*)d_in[20];

  float* ws    = (float*)d_ws;
  float* slots = ws;            // B*S*64 = 7168
  float* gqk   = ws + 7168;     // B*8*64 = 8192
  float* sc    = gqk + 8192;    // B*8*2  = 256
  float* ACC   = sc + 256;      // B*8*64 = 8192
  float* Zg    = ACC + 8192;    // B*8    = 128

  float* out = (float*)d_out;

#define SLOT_ARGS                                                          \
  slots_init, slots_mu, slots_lsig, ln_slot_g, ln_slot_b, ln_mlp_g,        \
      ln_mlp_b, ln_in_g, ln_in_b, Wq, Wk, Wv, W_ih, W_hh, b_ih, b_hh, W1,  \
      b1, W2, b2, slots, gqk, sc, ACC, Zg, out

  k_slot<<<112, 64, 0, stream>>>(0, SLOT_ARGS);
  for (int it = 0; it < 3; ++it) {
    k_main<<<BB * BPB, 256, 0, stream>>>(inputs, gqk, sc, ACC, Zg);
    k_slot<<<112, 64, 0, stream>>>(it == 2 ? 2 : 1, SLOT_ARGS);
  }
#undef SLOT_ARGS
}